// Round 17
// baseline (100.547 us; speedup 1.0000x reference)
//
#include <hip/hip_runtime.h>

struct PrepPtrs {
  const float* W[7]; const float* Bv[7]; const float* F; const float* fb;
  const float* W8; const float* B8; const float* W9; const float* B9;
  const float* W10; const float* B10;
};

// state-chunk swizzle (KA/KB): fold bits 3-4 into bits 0-1.
// NOT linear over +1 (cz(pb+1) = cz(pb) ^ 1 for even pb — the R16 bug).
// Linear over +N when N has no bits 0-5 (no carry into bits 3-4).
__device__ __forceinline__ int cz(int c) { return c ^ ((c >> 3) & 3); }

__device__ __forceinline__ float4 relu4(float4 a) {
  return make_float4(fmaxf(a.x,0.f), fmaxf(a.y,0.f), fmaxf(a.z,0.f), fmaxf(a.w,0.f));
}
__device__ __forceinline__ void fma4(float4& acc, float s, const float4& wv) {
  acc.x = fmaf(s, wv.x, acc.x); acc.y = fmaf(s, wv.y, acc.y);
  acc.z = fmaf(s, wv.z, acc.z); acc.w = fmaf(s, wv.w, acc.w);
}
__device__ __forceinline__ float4 add4(float4 a, float4 b) {
  return make_float4(a.x+b.x, a.y+b.y, a.z+b.z, a.w+b.w);
}

// 4-way-split butterfly apply (4 independent accumulator chains)
__device__ __forceinline__ float4 entApply(const float4* __restrict__ e4,
                                           float4 A0, float4 A1,
                                           float4 C0, float4 C1) {
  float4 a0 = e4[16];
  float4 a1 = make_float4(0.f, 0.f, 0.f, 0.f);
  float4 a2 = make_float4(0.f, 0.f, 0.f, 0.f);
  float4 a3 = make_float4(0.f, 0.f, 0.f, 0.f);
  fma4(a0, A0.x, e4[0]);  fma4(a1, A0.y, e4[1]);  fma4(a2, A0.z, e4[2]);  fma4(a3, A0.w, e4[3]);
  fma4(a0, A1.x, e4[4]);  fma4(a1, A1.y, e4[5]);  fma4(a2, A1.z, e4[6]);  fma4(a3, A1.w, e4[7]);
  fma4(a0, C0.x, e4[8]);  fma4(a1, C0.y, e4[9]);  fma4(a2, C0.z, e4[10]); fma4(a3, C0.w, e4[11]);
  fma4(a0, C1.x, e4[12]); fma4(a1, C1.y, e4[13]); fma4(a2, C1.z, e4[14]); fma4(a3, C1.w, e4[15]);
  return relu4(add4(add4(a0, a1), add4(a2, a3)));
}

// ---------------- prep: pack ALL weights into 80-float (k,th) entries (unchanged) ------
__global__ void bfly_prep(PrepPtrs P, float* __restrict__ wt) {
  int e = blockIdx.x * 256 + threadIdx.x;
  if (e >= 4094 * 68) return;
  int ent = e / 68, r = e % 68, dd = r & 3;
  const float* Ws; const float* Bs; int th;
  if (ent < 62) {
    if (ent < 60) {
      int lvl, base;
      if (ent < 4)       { lvl = 1; base = 0;  }
      else if (ent < 12) { lvl = 2; base = 4;  }
      else if (ent < 28) { lvl = 3; base = 12; }
      else               { lvl = 4; base = 28; }
      int k = (ent - base) >> 1; th = ent & 1;
      Ws = P.W[lvl-1] + k*128; Bs = P.Bv[lvl-1] + k*8;
    } else {
      th = ent - 60; Ws = P.F; Bs = P.fb;
    }
  } else if (ent < 510) {
    int eb = ent - 62;
    int q = eb / 56, rem = eb % 56;
    int lvl, Kl, base;
    if (rem < 8)       { lvl = 5; Kl = 4;  base = 0;  }
    else if (rem < 24) { lvl = 6; Kl = 8;  base = 8;  }
    else               { lvl = 7; Kl = 16; base = 24; }
    int rr = rem - base; int lk = rr >> 1; th = rr & 1;
    int kg = q * Kl + lk;
    Ws = P.W[lvl-1] + kg*128; Bs = P.Bv[lvl-1] + kg*8;
  } else if (ent < 1022) {
    int ec = ent - 510; int k = ec >> 1; th = ec & 1;
    Ws = P.W8 + k*128; Bs = P.B8 + k*8;
  } else if (ent < 2046) {
    int ec = ent - 1022; int k = ec >> 1; th = ec & 1;
    Ws = P.W9 + k*128; Bs = P.B9 + k*8;
  } else {
    int ec = ent - 2046; int k = ec >> 1; th = ec & 1;
    Ws = P.W10 + k*128; Bs = P.B10 + k*8;
  }
  float v;
  if (r < 64) { int s = r >> 5, c = (r >> 2) & 7; v = Ws[s*64 + c*8 + th*4 + dd]; }
  else v = Bs[th*4 + dd];
  wt[ent * 80 + r] = v;
}

// ---------------- KA levels: position-major lanes, 4 combos share the 4 parent reads ----
// wave w -> (kp, t-block); lane = t. Reads: cz base; C-pair via ^1 (NOT +1);
// plane offset +1024 is cz-linear. Writes: cz base + offsets kk*Tc (Tc>=64) and
// th*1024, both cz-linear.
template<int L>
__device__ __forceinline__ void ka_level2(const float4* __restrict__ src,
                                          float4* __restrict__ dst,
                                          const float4* __restrict__ wt4,
                                          int lane, int w) {
  constexpr int Tc = 1024 >> L;
  constexpr int entBase = ((1 << L) - 2) * 2;
  constexpr int TB = 1 << (4 - L);          // t-blocks per kp: 8,4,2,1
  const int kp = w >> (4 - L);
  const int tb = w & (TB - 1);
  const int t = lane + tb * 64;
  const int pb = kp * (2 * Tc) + 2 * t;     // even
  const int cb = cz(pb);
  const int cb1 = cb ^ 1;                   // cz(pb+1) == cz(pb)^1 for even pb
  float4 A0 = src[cb],        C0 = src[cb1];
  float4 A1 = src[cb + 1024], C1 = src[cb1 + 1024];
  float4* pD = dst + cz(2 * kp * Tc + t);
#pragma unroll
  for (int kk = 0; kk < 2; ++kk)
#pragma unroll
    for (int th = 0; th < 2; ++th) {
      const float4* e4 = wt4 + (entBase + (2 * kp + kk) * 2 + th) * 20;  // uniform s_load
      pD[kk * Tc + th * 1024] = entApply(e4, A0, A1, C0, C1);
    }
}

__global__ __launch_bounds__(512, 2) void bfly_ka(
    const float* __restrict__ x, const float* __restrict__ wt,
    float* __restrict__ st1)
{
  __shared__ float4 sA[2048], sB[2048];
  const int tid = threadIdx.x, b = blockIdx.x;
  const int lane = tid & 63;
  const int w = __builtin_amdgcn_readfirstlane(tid >> 6);
  const int th = w & 1, wq = w >> 1;
  const float4* wt4 = (const float4*)wt;

  { // conv (unchanged): wave = (th, wq), entry uniform, x from global
    const float4* e4 = wt4 + (60 + th) * 20;
    const float* xb = x + (size_t)b * 16384;
#pragma unroll
    for (int i = 0; i < 4; ++i) {
      int n = lane + wq * 64 + i * 256;
      const float4* xr = (const float4*)(xb + n * 16);
      float4 x0 = xr[0], x1 = xr[1], x2 = xr[2], x3 = xr[3];
      sA[cz(th * 1024 + n)] = entApply(e4, x0, x1, x2, x3);
    }
  }
  __syncthreads();
  ka_level2<1>(sA, sB, wt4, lane, w); __syncthreads();
  ka_level2<2>(sB, sA, wt4, lane, w); __syncthreads();
  ka_level2<3>(sA, sB, wt4, lane, w); __syncthreads();
  ka_level2<4>(sB, sA, wt4, lane, w); __syncthreads();

  float4* o4 = (float4*)st1;
#pragma unroll
  for (int it = 0; it < 4; ++it) {
    int o = tid + it * 512;
    int t4 = o & 63, k4 = (o >> 6) & 15, h = o >> 10;
    o4[((size_t)(h * 16 + k4) * 1024 + b) * 64 + t4] = sA[cz(o)];
  }
}

// ---------------- KB: levels 5..7, IN-PLACE single 32KB buffer ----------------
// Wave's write-region == read-region; all 4 parent reads precede all writes in
// wave program order -> in-place safe. Barriers only between levels.
template<int LV>
__device__ __forceinline__ void kb_level2(float4* __restrict__ s,
                                          const float4* __restrict__ wb4,
                                          int lane, int w) {
  constexpr int Tc = 1 << (10 - LV);        // 32,16,8
  constexpr int entB = (LV == 5) ? 0 : (LV == 6) ? 8 : 24;
  int kp, bl, t;
  if constexpr (LV == 5)      { kp = w >> 2; bl = ((w & 3) << 1) | (lane >> 5); t = lane & 31; }
  else if constexpr (LV == 6) { kp = w >> 1; bl = ((w & 1) << 2) | (lane >> 4); t = lane & 15; }
  else                        { kp = w;      bl = lane >> 3;                    t = lane & 7;  }
  const int pb = bl * 256 + kp * (2 * Tc) + 2 * t;   // even
  const int cb = cz(pb);
  const int cb1 = cb ^ 1;                   // cz(pb+1) == cz(pb)^1 for even pb
  float4 A0 = s[cb],       C0 = s[cb1];
  float4 A1 = s[cb + 128], C1 = s[cb1 + 128];
#pragma unroll
  for (int kk = 0; kk < 2; ++kk) {
    float4* pD = s + cz(bl * 256 + (2 * kp + kk) * Tc + t);   // Tc<64 -> cz per kk
#pragma unroll
    for (int th = 0; th < 2; ++th) {
      const float4* e4 = wb4 + (entB + (2 * kp + kk) * 2 + th) * 20;  // uniform s_load
      pD[th * 128] = entApply(e4, A0, A1, C0, C1);
    }
  }
}

__global__ __launch_bounds__(512, 3) void bfly_kb(
    const float* __restrict__ st1, const float* __restrict__ wt,
    float* __restrict__ st2)
{
  __shared__ float4 s0[2048];                // single buffer, in-place levels
  const int tid = threadIdx.x;
  const int q = blockIdx.x, bt = blockIdx.y;
  const int lane = tid & 63;
  const int w = __builtin_amdgcn_readfirstlane(tid >> 6);
  const float4* wb4 = (const float4*)wt + 1240 + q * 56 * 20;
  const float4* i4 = (const float4*)st1;

#pragma unroll
  for (int it = 0; it < 4; ++it) {
    int o = tid + it * 512;
    int t4 = o & 63, lk4 = (o >> 6) & 1, h = (o >> 7) & 1, bl = o >> 8;
    float4 v = i4[((size_t)(h * 16 + 2 * q + lk4) * 1024 + bt * 8 + bl) * 64 + t4];
    s0[cz(bl * 256 + h * 128 + lk4 * 64 + t4)] = v;
  }
  __syncthreads();
  kb_level2<5>(s0, wb4, lane, w); __syncthreads();
  kb_level2<6>(s0, wb4, lane, w); __syncthreads();
  kb_level2<7>(s0, wb4, lane, w); __syncthreads();

  float4* o4 = (float4*)st2;
#pragma unroll
  for (int it = 0; it < 4; ++it) {
    int o = tid + it * 512;
    int bl = o & 7, t7 = (o >> 3) & 7, h = (o >> 6) & 1, lk7 = o >> 7;
    float4 v = s0[cz(bl * 256 + h * 128 + lk7 * 8 + t7)];
    o4[((size_t)((16 * q + lk7) * 8 + t7) * 2 + h) * 1024 + bt * 8 + bl] = v;
  }
}

// ---------------- KC: levels 8..10 + dense, all-SGPR weights (unchanged from R15) -----
__global__ __launch_bounds__(512, 2) void bfly_kc(
    const float* __restrict__ st, const float* __restrict__ wt,
    const float* __restrict__ fea, float* __restrict__ out)
{
  __shared__ float4 sA[1024], sB[1024];
  const int tid = threadIdx.x;
  const int j = blockIdx.x, b0 = blockIdx.y * 64;
  const int bb = tid & 63;
  const int w = __builtin_amdgcn_readfirstlane(tid >> 6);
  const float4* wt4 = (const float4*)wt;

  {
    const float4* s4 = (const float4*)st;
#pragma unroll
    for (int it = 0; it < 2; ++it) {
      int idx = tid + it * 512;
      int bl = idx & 63, h = (idx >> 6) & 1, t = idx >> 7;
      sA[h * 512 + t * 64 + bl] = s4[((size_t)((j * 8 + t) * 2 + h)) * 1024 + b0 + bl];
    }
  }
  __syncthreads();

#pragma unroll
  for (int ii = 0; ii < 2; ++ii) {
    int s = w + ii * 8;
    int th = s >> 3, k = (s >> 2) & 1, t = s & 3;
    const float4* e4 = wt4 + (510 + (2 * j + k) * 2 + th) * 20;
    float4 A0 = sA[(2*t) * 64 + bb],   A1 = sA[512 + (2*t) * 64 + bb];
    float4 C0 = sA[(2*t+1) * 64 + bb], C1 = sA[512 + (2*t+1) * 64 + bb];
    sB[th * 512 + (2*t + k) * 64 + bb] = entApply(e4, A0, A1, C0, C1);
  }
  __syncthreads();
#pragma unroll
  for (int ii = 0; ii < 2; ++ii) {
    int s = w + ii * 8;
    int th = s >> 3, k9 = (s >> 1) & 3, t9 = s & 1;
    const float4* e4 = wt4 + (1022 + (4 * j + k9) * 2 + th) * 20;
    int p0 = 4 * t9 + (k9 >> 1), p1 = p0 + 2;
    float4 A0 = sB[p0 * 64 + bb], A1 = sB[512 + p0 * 64 + bb];
    float4 C0 = sB[p1 * 64 + bb], C1 = sB[512 + p1 * 64 + bb];
    sA[th * 512 + (t9 * 4 + k9) * 64 + bb] = entApply(e4, A0, A1, C0, C1);
  }
  __syncthreads();
#pragma unroll
  for (int ii = 0; ii < 2; ++ii) {
    int s = w + ii * 8;
    int th = s >> 3, k10 = s & 7;
    const float4* e4 = wt4 + (2046 + (8 * j + k10) * 2 + th) * 20;
    int p0 = k10 >> 1, p1 = p0 + 4;
    float4 A0 = sA[p0 * 64 + bb], A1 = sA[512 + p0 * 64 + bb];
    float4 C0 = sA[p1 * 64 + bb], C1 = sA[512 + p1 * 64 + bb];
    sB[th * 512 + k10 * 64 + bb] = entApply(e4, A0, A1, C0, C1);
  }
  __syncthreads();
  {
    int cc = tid & 31, bgrp = tid >> 5;
    int k = cc >> 2, fq = cc & 3;
    const float* fp = fea + (size_t)(j * 8 + k) * 128 + fq * 4;
    float4 f0 = *(const float4*)(fp);        float4 f1 = *(const float4*)(fp + 16);
    float4 f2 = *(const float4*)(fp + 32);   float4 f3 = *(const float4*)(fp + 48);
    float4 f4_ = *(const float4*)(fp + 64);  float4 f5 = *(const float4*)(fp + 80);
    float4 f6 = *(const float4*)(fp + 96);   float4 f7 = *(const float4*)(fp + 112);
#pragma unroll
    for (int it = 0; it < 4; ++it) {
      int b_l = bgrp + it * 16;
      float4 s0v = sB[k * 64 + b_l];
      float4 s1v = sB[512 + k * 64 + b_l];
      float4 a0 = make_float4(0.f,0.f,0.f,0.f), a1 = make_float4(0.f,0.f,0.f,0.f);
      float4 a2 = make_float4(0.f,0.f,0.f,0.f), a3 = make_float4(0.f,0.f,0.f,0.f);
      fma4(a0, s0v.x, f0);  fma4(a1, s0v.y, f1);
      fma4(a2, s0v.z, f2);  fma4(a3, s0v.w, f3);
      fma4(a0, s1v.x, f4_); fma4(a1, s1v.y, f5);
      fma4(a2, s1v.z, f6);  fma4(a3, s1v.w, f7);
      float4 acc = add4(add4(a0, a1), add4(a2, a3));
      *(float4*)(out + ((size_t)(b0 + b_l)) * 16384 + j * 128 + k * 16 + fq * 4) = acc;
    }
  }
}

extern "C" void kernel_launch(void* const* d_in, const int* in_sizes, int n_in,
                              void* d_out, int out_size, void* d_ws, size_t ws_size,
                              hipStream_t stream) {
  const float* x  = (const float*)d_in[0];
  PrepPtrs P;
  P.F  = (const float*)d_in[1];
  P.fb = (const float*)d_in[2];
  for (int l = 0; l < 7; ++l) {
    P.W[l]  = (const float*)d_in[3 + 2 * l];
    P.Bv[l] = (const float*)d_in[4 + 2 * l];
  }
  P.W8  = (const float*)d_in[17];
  P.B8  = (const float*)d_in[18];
  P.W9  = (const float*)d_in[19];
  P.B9  = (const float*)d_in[20];
  P.W10 = (const float*)d_in[21];
  P.B10 = (const float*)d_in[22];
  const float* fea = (const float*)d_in[23];
  float* wt  = (float*)d_ws;                 // 4094 entries x 80 floats = 1.31 MB
  float* st2 = (float*)d_ws + 393216;        // 33.5 MB level-7 state [j][t][h][b]
  float* st1 = (float*)d_out;                // 33.5 MB level-4 state (KC overwrites d_out)
  float* out = (float*)d_out;

  bfly_prep<<<dim3(1088), dim3(256), 0, stream>>>(P, wt);
  bfly_ka<<<dim3(1024), dim3(512), 0, stream>>>(x, wt, st1);
  bfly_kb<<<dim3(8, 128), dim3(512), 0, stream>>>(st1, wt, st2);
  bfly_kc<<<dim3(128, 16), dim3(512), 0, stream>>>(st2, wt, fea, out);
}

// Round 18
// 93.072 us; speedup vs baseline: 1.0803x; 1.0803x over previous
//
#include <hip/hip_runtime.h>

struct PrepPtrs {
  const float* W[7]; const float* Bv[7]; const float* F; const float* fb;
  const float* W8; const float* B8; const float* W9; const float* B9;
  const float* W10; const float* B10;
};

// state-chunk swizzle: fold bits 3-4 into bits 0-1.
// cz(pb+1) = cz(pb)^1 for even pb (NOT +1). Linear over +N with no bits 0-5.
__device__ __forceinline__ int cz(int c) { return c ^ ((c >> 3) & 3); }

__device__ __forceinline__ float4 relu4(float4 a) {
  return make_float4(fmaxf(a.x,0.f), fmaxf(a.y,0.f), fmaxf(a.z,0.f), fmaxf(a.w,0.f));
}
__device__ __forceinline__ void fma4(float4& acc, float s, const float4& wv) {
  acc.x = fmaf(s, wv.x, acc.x); acc.y = fmaf(s, wv.y, acc.y);
  acc.z = fmaf(s, wv.z, acc.z); acc.w = fmaf(s, wv.w, acc.w);
}
__device__ __forceinline__ float4 add4(float4 a, float4 b) {
  return make_float4(a.x+b.x, a.y+b.y, a.z+b.z, a.w+b.w);
}

// 4-way-split butterfly apply (4 independent accumulator chains)
__device__ __forceinline__ float4 entApply(const float4* __restrict__ e4,
                                           float4 A0, float4 A1,
                                           float4 C0, float4 C1) {
  float4 a0 = e4[16];
  float4 a1 = make_float4(0.f, 0.f, 0.f, 0.f);
  float4 a2 = make_float4(0.f, 0.f, 0.f, 0.f);
  float4 a3 = make_float4(0.f, 0.f, 0.f, 0.f);
  fma4(a0, A0.x, e4[0]);  fma4(a1, A0.y, e4[1]);  fma4(a2, A0.z, e4[2]);  fma4(a3, A0.w, e4[3]);
  fma4(a0, A1.x, e4[4]);  fma4(a1, A1.y, e4[5]);  fma4(a2, A1.z, e4[6]);  fma4(a3, A1.w, e4[7]);
  fma4(a0, C0.x, e4[8]);  fma4(a1, C0.y, e4[9]);  fma4(a2, C0.z, e4[10]); fma4(a3, C0.w, e4[11]);
  fma4(a0, C1.x, e4[12]); fma4(a1, C1.y, e4[13]); fma4(a2, C1.z, e4[14]); fma4(a3, C1.w, e4[15]);
  return relu4(add4(add4(a0, a1), add4(a2, a3)));
}

// ---------------- prep: pack ALL weights into 80-float (k,th) entries (unchanged) ------
__global__ void bfly_prep(PrepPtrs P, float* __restrict__ wt) {
  int e = blockIdx.x * 256 + threadIdx.x;
  if (e >= 4094 * 68) return;
  int ent = e / 68, r = e % 68, dd = r & 3;
  const float* Ws; const float* Bs; int th;
  if (ent < 62) {
    if (ent < 60) {
      int lvl, base;
      if (ent < 4)       { lvl = 1; base = 0;  }
      else if (ent < 12) { lvl = 2; base = 4;  }
      else if (ent < 28) { lvl = 3; base = 12; }
      else               { lvl = 4; base = 28; }
      int k = (ent - base) >> 1; th = ent & 1;
      Ws = P.W[lvl-1] + k*128; Bs = P.Bv[lvl-1] + k*8;
    } else {
      th = ent - 60; Ws = P.F; Bs = P.fb;
    }
  } else if (ent < 510) {
    int eb = ent - 62;
    int q = eb / 56, rem = eb % 56;
    int lvl, Kl, base;
    if (rem < 8)       { lvl = 5; Kl = 4;  base = 0;  }
    else if (rem < 24) { lvl = 6; Kl = 8;  base = 8;  }
    else               { lvl = 7; Kl = 16; base = 24; }
    int rr = rem - base; int lk = rr >> 1; th = rr & 1;
    int kg = q * Kl + lk;
    Ws = P.W[lvl-1] + kg*128; Bs = P.Bv[lvl-1] + kg*8;
  } else if (ent < 1022) {
    int ec = ent - 510; int k = ec >> 1; th = ec & 1;
    Ws = P.W8 + k*128; Bs = P.B8 + k*8;
  } else if (ent < 2046) {
    int ec = ent - 1022; int k = ec >> 1; th = ec & 1;
    Ws = P.W9 + k*128; Bs = P.B9 + k*8;
  } else {
    int ec = ent - 2046; int k = ec >> 1; th = ec & 1;
    Ws = P.W10 + k*128; Bs = P.B10 + k*8;
  }
  float v;
  if (r < 64) { int s = r >> 5, c = (r >> 2) & 7; v = Ws[s*64 + c*8 + th*4 + dd]; }
  else v = Bs[th*4 + dd];
  wt[ent * 80 + r] = v;
}

// ---------------- KA: conv + levels 1..4 on a HALF-tree (t-separable) ----------------
// Block = (batch, half). State: 512 rows, plane th at th*512 + (k*T + t), T = 512>>L.
// 32 KB ping-pong -> 3 blocks/CU. R13-style: one wave-uniform entry per iter (s_load).
template<int L>
__device__ __forceinline__ void ka_level3(const float4* __restrict__ src,
                                          float4* __restrict__ dst,
                                          const float4* __restrict__ wt4,
                                          int lane, int w) {
  constexpr int T = 512 >> L;
  constexpr int entBase = ((1 << L) - 2) * 2;
  const int th = w & 1, wq = w >> 1;          // w in [0,8)
  if constexpr (L == 1) {
#pragma unroll
    for (int it = 0; it < 2; ++it) {
      const int k = wq & 1;
      const int t = lane + (wq >> 1) * 64 + it * 128;       // [0,256)
      const float4* e4 = wt4 + (entBase + k * 2 + th) * 20; // uniform -> s_load
      int pb = (k >> 1) * (2 * T) + 2 * t;
      int cb = cz(pb), cb1 = cb ^ 1;
      float4 A0 = src[cb], C0 = src[cb1], A1 = src[cb + 512], C1 = src[cb1 + 512];
      dst[cz(th * 512 + k * T + t)] = entApply(e4, A0, A1, C0, C1);
    }
  } else if constexpr (L == 2) {
#pragma unroll
    for (int it = 0; it < 2; ++it) {
      const int k = wq;                                     // [0,4)
      const int t = lane + it * 64;                         // [0,128)
      const float4* e4 = wt4 + (entBase + k * 2 + th) * 20;
      int pb = (k >> 1) * (2 * T) + 2 * t;
      int cb = cz(pb), cb1 = cb ^ 1;
      float4 A0 = src[cb], C0 = src[cb1], A1 = src[cb + 512], C1 = src[cb1 + 512];
      dst[cz(th * 512 + k * T + t)] = entApply(e4, A0, A1, C0, C1);
    }
  } else if constexpr (L == 3) {
#pragma unroll
    for (int ik = 0; ik < 2; ++ik) {
      const int k = wq + 4 * ik;                            // [0,8)
      const int t = lane;                                   // [0,64)
      const float4* e4 = wt4 + (entBase + k * 2 + th) * 20;
      int pb = (k >> 1) * (2 * T) + 2 * t;
      int cb = cz(pb), cb1 = cb ^ 1;
      float4 A0 = src[cb], C0 = src[cb1], A1 = src[cb + 512], C1 = src[cb1 + 512];
      dst[cz(th * 512 + k * T + t)] = entApply(e4, A0, A1, C0, C1);
    }
  } else {  // L == 4: T=32 < 64 lanes -> lane pairs duplicate (same addr, same value)
#pragma unroll
    for (int ik = 0; ik < 4; ++ik) {
      const int k = wq + 4 * ik;                            // [0,16)
      const int t = lane & 31;                              // duplicated across halves
      const float4* e4 = wt4 + (entBase + k * 2 + th) * 20;
      int pb = (k >> 1) * (2 * T) + 2 * t;
      int cb = cz(pb), cb1 = cb ^ 1;
      float4 A0 = src[cb], C0 = src[cb1], A1 = src[cb + 512], C1 = src[cb1 + 512];
      dst[cz(th * 512 + k * T + t)] = entApply(e4, A0, A1, C0, C1);
    }
  }
}

__global__ __launch_bounds__(512, 3) void bfly_ka(
    const float* __restrict__ x, const float* __restrict__ wt,
    float* __restrict__ st1)
{
  __shared__ float4 sA[1024], sB[1024];        // 32 KB total
  const int tid = threadIdx.x;
  const int b = blockIdx.x >> 1, half = blockIdx.x & 1;
  const int lane = tid & 63;
  const int w = __builtin_amdgcn_readfirstlane(tid >> 6);
  const int th = w & 1, wq = w >> 1;
  const float4* wt4 = (const float4*)wt;

  { // conv: 512 rows (leaves half*512 .. half*512+511)
    const float4* e4 = wt4 + (60 + th) * 20;
    const float* xb = x + (size_t)b * 16384 + half * 8192;
#pragma unroll
    for (int i = 0; i < 2; ++i) {
      int n = lane + wq * 64 + i * 256;        // [0,512)
      const float4* xr = (const float4*)(xb + n * 16);
      float4 x0 = xr[0], x1 = xr[1], x2 = xr[2], x3 = xr[3];
      sA[cz(th * 512 + n)] = entApply(e4, x0, x1, x2, x3);
    }
  }
  __syncthreads();
  ka_level3<1>(sA, sB, wt4, lane, w); __syncthreads();
  ka_level3<2>(sB, sA, wt4, lane, w); __syncthreads();
  ka_level3<3>(sA, sB, wt4, lane, w); __syncthreads();
  ka_level3<4>(sB, sA, wt4, lane, w); __syncthreads();

  // level-4 state in sA: row = k4*32 + t4l, plane h. st1[h][k4][b][half*32 + t4l].
  float4* o4 = (float4*)st1;
#pragma unroll
  for (int it = 0; it < 2; ++it) {
    int o = tid + it * 512;                    // [0,1024)
    int t4l = o & 31, k4 = (o >> 5) & 15, h = o >> 9;
    float4 v = sA[cz(h * 512 + k4 * 32 + t4l)];
    o4[((size_t)(h * 16 + k4) * 1024 + b) * 64 + half * 32 + t4l] = v;
  }
}

// ---------------- KB: levels 5..7, IN-PLACE single 32KB buffer (R17, validated) --------
template<int LV>
__device__ __forceinline__ void kb_level2(float4* __restrict__ s,
                                          const float4* __restrict__ wb4,
                                          int lane, int w) {
  constexpr int Tc = 1 << (10 - LV);        // 32,16,8
  constexpr int entB = (LV == 5) ? 0 : (LV == 6) ? 8 : 24;
  int kp, bl, t;
  if constexpr (LV == 5)      { kp = w >> 2; bl = ((w & 3) << 1) | (lane >> 5); t = lane & 31; }
  else if constexpr (LV == 6) { kp = w >> 1; bl = ((w & 1) << 2) | (lane >> 4); t = lane & 15; }
  else                        { kp = w;      bl = lane >> 3;                    t = lane & 7;  }
  const int pb = bl * 256 + kp * (2 * Tc) + 2 * t;   // even
  const int cb = cz(pb);
  const int cb1 = cb ^ 1;
  float4 A0 = s[cb],       C0 = s[cb1];
  float4 A1 = s[cb + 128], C1 = s[cb1 + 128];
#pragma unroll
  for (int kk = 0; kk < 2; ++kk) {
    float4* pD = s + cz(bl * 256 + (2 * kp + kk) * Tc + t);
#pragma unroll
    for (int th = 0; th < 2; ++th) {
      const float4* e4 = wb4 + (entB + (2 * kp + kk) * 2 + th) * 20;  // uniform s_load
      pD[th * 128] = entApply(e4, A0, A1, C0, C1);
    }
  }
}

__global__ __launch_bounds__(512, 3) void bfly_kb(
    const float* __restrict__ st1, const float* __restrict__ wt,
    float* __restrict__ st2)
{
  __shared__ float4 s0[2048];                // single buffer, in-place levels
  const int tid = threadIdx.x;
  const int q = blockIdx.x, bt = blockIdx.y;
  const int lane = tid & 63;
  const int w = __builtin_amdgcn_readfirstlane(tid >> 6);
  const float4* wb4 = (const float4*)wt + 1240 + q * 56 * 20;
  const float4* i4 = (const float4*)st1;

#pragma unroll
  for (int it = 0; it < 4; ++it) {
    int o = tid + it * 512;
    int t4 = o & 63, lk4 = (o >> 6) & 1, h = (o >> 7) & 1, bl = o >> 8;
    float4 v = i4[((size_t)(h * 16 + 2 * q + lk4) * 1024 + bt * 8 + bl) * 64 + t4];
    s0[cz(bl * 256 + h * 128 + lk4 * 64 + t4)] = v;
  }
  __syncthreads();
  kb_level2<5>(s0, wb4, lane, w); __syncthreads();
  kb_level2<6>(s0, wb4, lane, w); __syncthreads();
  kb_level2<7>(s0, wb4, lane, w); __syncthreads();

  float4* o4 = (float4*)st2;
#pragma unroll
  for (int it = 0; it < 4; ++it) {
    int o = tid + it * 512;
    int bl = o & 7, t7 = (o >> 3) & 7, h = (o >> 6) & 1, lk7 = o >> 7;
    float4 v = s0[cz(bl * 256 + h * 128 + lk7 * 8 + t7)];
    o4[((size_t)((16 * q + lk7) * 8 + t7) * 2 + h) * 1024 + bt * 8 + bl] = v;
  }
}

// ---------------- KC: levels 8..10 + dense, all-SGPR weights (unchanged) ----------
__global__ __launch_bounds__(512, 2) void bfly_kc(
    const float* __restrict__ st, const float* __restrict__ wt,
    const float* __restrict__ fea, float* __restrict__ out)
{
  __shared__ float4 sA[1024], sB[1024];
  const int tid = threadIdx.x;
  const int j = blockIdx.x, b0 = blockIdx.y * 64;
  const int bb = tid & 63;
  const int w = __builtin_amdgcn_readfirstlane(tid >> 6);
  const float4* wt4 = (const float4*)wt;

  {
    const float4* s4 = (const float4*)st;
#pragma unroll
    for (int it = 0; it < 2; ++it) {
      int idx = tid + it * 512;
      int bl = idx & 63, h = (idx >> 6) & 1, t = idx >> 7;
      sA[h * 512 + t * 64 + bl] = s4[((size_t)((j * 8 + t) * 2 + h)) * 1024 + b0 + bl];
    }
  }
  __syncthreads();

#pragma unroll
  for (int ii = 0; ii < 2; ++ii) {
    int s = w + ii * 8;
    int th = s >> 3, k = (s >> 2) & 1, t = s & 3;
    const float4* e4 = wt4 + (510 + (2 * j + k) * 2 + th) * 20;
    float4 A0 = sA[(2*t) * 64 + bb],   A1 = sA[512 + (2*t) * 64 + bb];
    float4 C0 = sA[(2*t+1) * 64 + bb], C1 = sA[512 + (2*t+1) * 64 + bb];
    sB[th * 512 + (2*t + k) * 64 + bb] = entApply(e4, A0, A1, C0, C1);
  }
  __syncthreads();
#pragma unroll
  for (int ii = 0; ii < 2; ++ii) {
    int s = w + ii * 8;
    int th = s >> 3, k9 = (s >> 1) & 3, t9 = s & 1;
    const float4* e4 = wt4 + (1022 + (4 * j + k9) * 2 + th) * 20;
    int p0 = 4 * t9 + (k9 >> 1), p1 = p0 + 2;
    float4 A0 = sB[p0 * 64 + bb], A1 = sB[512 + p0 * 64 + bb];
    float4 C0 = sB[p1 * 64 + bb], C1 = sB[512 + p1 * 64 + bb];
    sA[th * 512 + (t9 * 4 + k9) * 64 + bb] = entApply(e4, A0, A1, C0, C1);
  }
  __syncthreads();
#pragma unroll
  for (int ii = 0; ii < 2; ++ii) {
    int s = w + ii * 8;
    int th = s >> 3, k10 = s & 7;
    const float4* e4 = wt4 + (2046 + (8 * j + k10) * 2 + th) * 20;
    int p0 = k10 >> 1, p1 = p0 + 4;
    float4 A0 = sA[p0 * 64 + bb], A1 = sA[512 + p0 * 64 + bb];
    float4 C0 = sA[p1 * 64 + bb], C1 = sA[512 + p1 * 64 + bb];
    sB[th * 512 + k10 * 64 + bb] = entApply(e4, A0, A1, C0, C1);
  }
  __syncthreads();
  {
    int cc = tid & 31, bgrp = tid >> 5;
    int k = cc >> 2, fq = cc & 3;
    const float* fp = fea + (size_t)(j * 8 + k) * 128 + fq * 4;
    float4 f0 = *(const float4*)(fp);        float4 f1 = *(const float4*)(fp + 16);
    float4 f2 = *(const float4*)(fp + 32);   float4 f3 = *(const float4*)(fp + 48);
    float4 f4_ = *(const float4*)(fp + 64);  float4 f5 = *(const float4*)(fp + 80);
    float4 f6 = *(const float4*)(fp + 96);   float4 f7 = *(const float4*)(fp + 112);
#pragma unroll
    for (int it = 0; it < 4; ++it) {
      int b_l = bgrp + it * 16;
      float4 s0v = sB[k * 64 + b_l];
      float4 s1v = sB[512 + k * 64 + b_l];
      float4 a0 = make_float4(0.f,0.f,0.f,0.f), a1 = make_float4(0.f,0.f,0.f,0.f);
      float4 a2 = make_float4(0.f,0.f,0.f,0.f), a3 = make_float4(0.f,0.f,0.f,0.f);
      fma4(a0, s0v.x, f0);  fma4(a1, s0v.y, f1);
      fma4(a2, s0v.z, f2);  fma4(a3, s0v.w, f3);
      fma4(a0, s1v.x, f4_); fma4(a1, s1v.y, f5);
      fma4(a2, s1v.z, f6);  fma4(a3, s1v.w, f7);
      float4 acc = add4(add4(a0, a1), add4(a2, a3));
      *(float4*)(out + ((size_t)(b0 + b_l)) * 16384 + j * 128 + k * 16 + fq * 4) = acc;
    }
  }
}

extern "C" void kernel_launch(void* const* d_in, const int* in_sizes, int n_in,
                              void* d_out, int out_size, void* d_ws, size_t ws_size,
                              hipStream_t stream) {
  const float* x  = (const float*)d_in[0];
  PrepPtrs P;
  P.F  = (const float*)d_in[1];
  P.fb = (const float*)d_in[2];
  for (int l = 0; l < 7; ++l) {
    P.W[l]  = (const float*)d_in[3 + 2 * l];
    P.Bv[l] = (const float*)d_in[4 + 2 * l];
  }
  P.W8  = (const float*)d_in[17];
  P.B8  = (const float*)d_in[18];
  P.W9  = (const float*)d_in[19];
  P.B9  = (const float*)d_in[20];
  P.W10 = (const float*)d_in[21];
  P.B10 = (const float*)d_in[22];
  const float* fea = (const float*)d_in[23];
  float* wt  = (float*)d_ws;                 // 4094 entries x 80 floats = 1.31 MB
  float* st2 = (float*)d_ws + 393216;        // 33.5 MB level-7 state [j][t][h][b]
  float* st1 = (float*)d_out;                // 33.5 MB level-4 state (KC overwrites d_out)
  float* out = (float*)d_out;

  bfly_prep<<<dim3(1088), dim3(256), 0, stream>>>(P, wt);
  bfly_ka<<<dim3(2048), dim3(512), 0, stream>>>(x, wt, st1);
  bfly_kb<<<dim3(8, 128), dim3(512), 0, stream>>>(st1, wt, st2);
  bfly_kc<<<dim3(128, 16), dim3(512), 0, stream>>>(st2, wt, fea, out);
}